// Round 7
// baseline (392.723 us; speedup 1.0000x reference)
//
#include <hip/hip_runtime.h>
#include <stdint.h>

// RT-DETR post-processing, round 7: SINGLE fused kernel.
// 2048 blocks x 256: each scans its (row,part) chunk with the proven R5
// gate (raw logit > 2.6, monotone in sigmoid), writes a private segment +
// count. Then threadfence + agent-scope ticket fetch_add(done[row]); the
// block with (ticket & 15)==15 is the row's LAST finisher and inline-ranks
// the row (512-bin hist cut -> keep ~305 -> exact rank -> box epilogue).
// The mod-16 residue claim needs NO initialization (any 16 consecutive
// tickets hit residue 15 exactly once), so no memset and it is stable
// across 0xAA poisons and graph replays. Exact full-row fallback inlined.
// Selection semantics (proven R1-R6, absmax 0): top-300 by composite key
// (sigmoid_bits<<32)|~idx == (score desc, index asc) exactly.

#define BATCH 128
#define NCLS 80
#define NQ 2000
#define ROW (NQ * NCLS)     // 160000
#define TOPK 300
#define SPLIT 16
#define CHUNK (ROW / SPLIT) // 10000
#define SEGCAP 128
#define CAP (SPLIT * SEGCAP) // 2048
#define KEEPCAP 512
#define LOGIT_T 2.6f
#define NTHR 256

// ws layout (bytes), nothing pre-zeroed (done_g uses residue trick):
//   cand : [BATCH][SPLIT][SEGCAP] u64 @ 0       (2 MB)
//   cnt  : [BATCH][SPLIT] u32        @ WS_CNT   (8 KB)
//   done : [BATCH] u32               @ WS_DONE  (512 B)
#define WS_CAND 0
#define WS_CNT  (BATCH * CAP * 8)
#define WS_DONE (WS_CNT + BATCH * SPLIT * 4)

__device__ __forceinline__ uint32_t score_bits(float x) {
  float e = expf(-fabsf(x));
  float num = (x >= 0.f) ? 1.f : e;
  float s = num / (1.f + e);
  return __float_as_uint(s);
}

__device__ __forceinline__ uint32_t bin512(uint32_t bits) {
  // monotone over the candidate range (sigmoid(2.6)=0.9309.. -> bits
  // 0x3F6E4xxx..0x3F7FFFFF: bit8 of bits>>12 preserved by &0x1FF)
  return (bits >= 0x3F800000u) ? 511u : ((bits >> 12) & 0x1FFu);
}

__global__ __launch_bounds__(NTHR, 8)
void rtdetr_fused(const float* __restrict__ logits,
                  const float* __restrict__ boxes,
                  const int* __restrict__ sizes,
                  float* __restrict__ out,
                  uint64_t* __restrict__ cand_g,
                  uint32_t* __restrict__ cnt_g,
                  uint32_t* __restrict__ done_g)
{
  __shared__ uint32_t lcnt, sh_win;
  const int row = blockIdx.x >> 4;          // SPLIT=16
  const int part = blockIdx.x & 15;
  const int tid = threadIdx.x;
  if (tid == 0) lcnt = 0;
  __syncthreads();

  // ---- scan phase (R5's proven inner loop, unchanged) ----
  {
    const float4* p = (const float4*)(logits + (size_t)row * ROW + part * CHUNK);
    uint64_t* seg = cand_g + ((size_t)row * SPLIT + part) * SEGCAP;
    const uint32_t base_idx = part * CHUNK;

    for (int pi = tid; pi < CHUNK / 8; pi += NTHR) {
      float4 v0 = p[pi * 2];
      float4 v1 = p[pi * 2 + 1];
      float m0 = fmaxf(fmaxf(v0.x, v0.y), fmaxf(v0.z, v0.w));
      float m1 = fmaxf(fmaxf(v1.x, v1.y), fmaxf(v1.z, v1.w));
      if (m0 > LOGIT_T) {
        #pragma unroll
        for (int c = 0; c < 4; ++c) {
          float x = (&v0.x)[c];
          if (x > LOGIT_T) {
            uint32_t pos = atomicAdd(&lcnt, 1u);
            uint32_t idx = base_idx + pi * 8 + c;
            if (pos < SEGCAP) seg[pos] = ((uint64_t)score_bits(x) << 32) | (uint32_t)~idx;
          }
        }
      }
      if (m1 > LOGIT_T) {
        #pragma unroll
        for (int c = 0; c < 4; ++c) {
          float x = (&v1.x)[c];
          if (x > LOGIT_T) {
            uint32_t pos = atomicAdd(&lcnt, 1u);
            uint32_t idx = base_idx + pi * 8 + 4 + c;
            if (pos < SEGCAP) seg[pos] = ((uint64_t)score_bits(x) << 32) | (uint32_t)~idx;
          }
        }
      }
    }
  }
  __syncthreads();

  // ---- publish + last-finisher claim (init-free residue ticket) ----
  if (tid == 0) {
    cnt_g[row * SPLIT + part] = lcnt;
    __threadfence();  // drain block's stores to L2; release below flushes L2
    uint32_t old = __hip_atomic_fetch_add(&done_g[row], 1u,
                                          __ATOMIC_ACQ_REL, __HIP_MEMORY_SCOPE_AGENT);
    sh_win = ((old & (SPLIT - 1u)) == (SPLIT - 1u)) ? 1u : 0u;
  }
  __syncthreads();
  if (!sh_win) return;

  // ================= winner: rank this row =================
  __shared__ uint32_t pc[SPLIT];
  __shared__ uint32_t hist[512];      // 2 KB
  __shared__ uint64_t keep[KEEPCAP];  // 4 KB
  __shared__ uint32_t sh_M, sh_bad, sh_B, keepcnt;
  __shared__ uint32_t fhist[2048];    // 8 KB (fallback)
  __shared__ uint32_t fh2[256];       // 1 KB (fallback)
  __shared__ uint32_t sh_T, sh_A, sh_T2, fcnt;

  const int b = row;
  float* out_labels = out;
  float4* out_boxes = (float4*)(out + BATCH * TOPK);
  float* out_scores = out + BATCH * TOPK + BATCH * TOPK * 4;
  const float4* brow = (const float4*)(boxes + (size_t)b * NQ * 4);
  const float img_h = (float)sizes[2 * b];
  const float img_w = (float)sizes[2 * b + 1];

  if (tid < SPLIT) pc[tid] = cnt_g[b * SPLIT + tid];
  for (int i = tid; i < 512; i += NTHR) hist[i] = 0;
  if (tid == 0) { keepcnt = 0; fcnt = 0; }
  __syncthreads();

  if (tid == 0) {
    uint32_t t = 0, bad = 0;
    #pragma unroll
    for (int pp2 = 0; pp2 < SPLIT; ++pp2) {
      uint32_t c = pc[pp2];
      if (c > SEGCAP) bad = 1;
      t += c;
    }
    sh_M = t;
    sh_bad = (bad || t < TOPK) ? 1u : 0u;
  }
  __syncthreads();

  bool fb = (sh_bad != 0);
  if (!fb) {
    const int pp = tid >> 4, jl = tid & 15;   // 16 threads per part
    const uint64_t* sgp = cand_g + ((size_t)b * SPLIT + pp) * SEGCAP;
    const int pcnt = (int)pc[pp];

    // pass A: 512-bin histogram of candidate score bits
    for (int j = jl; j < pcnt; j += 16)
      atomicAdd(&hist[bin512((uint32_t)(sgp[j] >> 32))], 1u);
    __syncthreads();

    // exact-bin cut via wave 0 (2-level suffix scan: 64 superbins x 8)
    if (tid < 64) {
      const int lane = tid;
      uint32_t s = 0;
      #pragma unroll
      for (int j = 0; j < 8; ++j) s += hist[lane * 8 + j];
      uint32_t suf = s;
      #pragma unroll
      for (int d = 1; d < 64; d <<= 1) {
        uint32_t o = __shfl_down(suf, d, 64);
        if (lane + d < 64) suf += o;
      }
      unsigned long long m = __ballot(suf >= (uint32_t)TOPK);
      int L = 63 - __builtin_clzll(m);
      uint32_t nxt = __shfl(suf, (L + 1) & 63, 64);
      uint32_t acc0 = (L < 63) ? nxt : 0u;
      uint32_t s2 = (lane < 8) ? hist[L * 8 + lane] : 0u;
      uint32_t suf2 = s2;
      #pragma unroll
      for (int d = 1; d < 8; d <<= 1) {
        uint32_t o = __shfl_down(suf2, d, 64);
        if (lane + d < 8) suf2 += o;
      }
      unsigned long long m2 = __ballot(lane < 8 && (acc0 + suf2) >= (uint32_t)TOPK);
      int Bl = 63 - __builtin_clzll(m2);
      if (lane == 0) sh_B = (uint32_t)(L * 8 + Bl);
    }
    __syncthreads();

    // pass B: compact keep set (superset of top-300, ~= 300 + bin width)
    const uint32_t B = sh_B;
    for (int j = jl; j < pcnt; j += 16) {
      uint64_t key = sgp[j];
      if (bin512((uint32_t)(key >> 32)) >= B) {
        uint32_t pos = atomicAdd(&keepcnt, 1u);
        if (pos < KEEPCAP) keep[pos] = key;
      }
    }
    __syncthreads();

    const uint32_t KN = keepcnt;
    if (KN <= KEEPCAP) {
      for (int i = tid; i < (int)KN; i += NTHR) {
        uint64_t key = keep[i];
        int rank = 0;
        for (uint32_t j = 0; j < KN; ++j) rank += (keep[j] > key) ? 1 : 0;
        if (rank < TOPK) {
          uint32_t bits = (uint32_t)(key >> 32);
          uint32_t idx = ~(uint32_t)(key & 0xFFFFFFFFull);
          int q = (int)(idx / NCLS);
          int cls = (int)idx - q * NCLS;
          float4 pb = brow[q];
          float x0 = fmaxf((pb.x - 0.5f * pb.z) * img_w, 0.f);
          float y0 = fmaxf((pb.y - 0.5f * pb.w) * img_h, 0.f);
          float w2 = fmaxf(pb.z * img_w, 1.f);
          float h2 = fmaxf(pb.w * img_h, 1.f);
          int o = b * TOPK + rank;
          out_labels[o] = (float)cls;
          out_boxes[o] = make_float4(x0, y0, w2, h2);
          out_scores[o] = __uint_as_float(bits);
        }
      }
      return;
    }
    fb = true;  // keep overflow (pathological): exact fallback below
  }

  // ======== exact full-row fallback (R1 structure, 2048 bins) ========
  const float4* row4 = (const float4*)(logits + (size_t)b * ROW);
  for (int i = tid; i < 2048; i += NTHR) fhist[i] = 0;
  __syncthreads();

  for (int i = tid; i < ROW / 4; i += NTHR) {
    float4 v = row4[i];
    #pragma unroll
    for (int c = 0; c < 4; ++c) {
      uint32_t bk = score_bits((&v.x)[c]) >> 19;   // monotone: bits < 0x3F800000
      bk = bk < 2048u ? bk : 2047u;
      atomicAdd(&fhist[bk], 1u);
    }
  }
  __syncthreads();

  if (tid < 64) {
    const int lane = tid;
    uint32_t s = 0;
    #pragma unroll
    for (int j = 0; j < 32; ++j) s += fhist[lane * 32 + j];
    uint32_t suf = s;
    #pragma unroll
    for (int d = 1; d < 64; d <<= 1) {
      uint32_t o = __shfl_down(suf, d, 64);
      if (lane + d < 64) suf += o;
    }
    unsigned long long m = __ballot(suf >= (uint32_t)TOPK);
    int L = 63 - __builtin_clzll(m);
    uint32_t nxt = __shfl(suf, (L + 1) & 63, 64);
    uint32_t acc0 = (L < 63) ? nxt : 0u;
    uint32_t s2 = (lane < 32) ? fhist[L * 32 + lane] : 0u;
    uint32_t suf2 = s2;
    #pragma unroll
    for (int d = 1; d < 32; d <<= 1) {
      uint32_t o = __shfl_down(suf2, d, 64);
      if (lane + d < 32) suf2 += o;
    }
    unsigned long long m2 = __ballot(lane < 32 && (acc0 + suf2) >= (uint32_t)TOPK);
    int Bl = 63 - __builtin_clzll(m2);
    uint32_t nxt2 = __shfl(suf2, (Bl + 1) & 63, 64);
    uint32_t A = acc0 + ((Bl < 31) ? nxt2 : 0u);
    if (lane == 0) { sh_T = (uint32_t)(L * 32 + Bl); sh_A = A; }
  }
  __syncthreads();

  const uint32_t T = sh_T, A = sh_A, Cc = fhist[T];
  uint64_t* crow = cand_g + (size_t)b * CAP;   // winner owns whole row region

  if (A + Cc <= CAP) {
    for (int i = tid; i < ROW / 4; i += NTHR) {
      float4 v = row4[i];
      #pragma unroll
      for (int c = 0; c < 4; ++c) {
        uint32_t bits = score_bits((&v.x)[c]);
        uint32_t bk = bits >> 19; bk = bk < 2048u ? bk : 2047u;
        if (bk >= T) {
          uint32_t pos = atomicAdd(&fcnt, 1u);
          if (pos < CAP) crow[pos] = ((uint64_t)bits << 32) | (uint32_t)~(uint32_t)(i * 4 + c);
        }
      }
    }
  } else {
    for (int i = tid; i < 256; i += NTHR) fh2[i] = 0;
    __syncthreads();
    for (int i = tid; i < ROW / 4; i += NTHR) {
      float4 v = row4[i];
      #pragma unroll
      for (int c = 0; c < 4; ++c) {
        uint32_t bits = score_bits((&v.x)[c]);
        uint32_t bk = bits >> 19; bk = bk < 2048u ? bk : 2047u;
        if (bk == T) atomicAdd(&fh2[(bits >> 11) & 0xFF], 1u);
      }
    }
    __syncthreads();
    if (tid < 64) {
      const int lane = tid;
      uint32_t h4 = 0;
      #pragma unroll
      for (int j = 0; j < 4; ++j) h4 += fh2[lane * 4 + j];
      uint32_t suf = h4;
      #pragma unroll
      for (int d = 1; d < 64; d <<= 1) {
        uint32_t o = __shfl_down(suf, d, 64);
        if (lane + d < 64) suf += o;
      }
      unsigned long long m = __ballot((A + suf) >= (uint32_t)TOPK);
      int g = 63 - __builtin_clzll(m);
      uint32_t nxtg = __shfl(suf, (g + 1) & 63, 64);
      uint32_t accg = A + ((g < 63) ? nxtg : 0u);
      uint32_t hb = (lane < 4) ? fh2[g * 4 + lane] : 0u;
      uint32_t sufb = hb;
      #pragma unroll
      for (int d = 1; d < 4; d <<= 1) {
        uint32_t o = __shfl_down(sufb, d, 64);
        if (lane + d < 4) sufb += o;
      }
      unsigned long long mb = __ballot(lane < 4 && (accg + sufb) >= (uint32_t)TOPK);
      int bin = 63 - __builtin_clzll(mb);
      if (lane == 0) sh_T2 = (uint32_t)(g * 4 + bin);
    }
    __syncthreads();
    const uint32_t T2v = sh_T2;
    for (int i = tid; i < ROW / 4; i += NTHR) {
      float4 v = row4[i];
      #pragma unroll
      for (int c = 0; c < 4; ++c) {
        uint32_t bits = score_bits((&v.x)[c]);
        uint32_t bk = bits >> 19; bk = bk < 2048u ? bk : 2047u;
        bool take = (bk > T) || (bk == T && ((bits >> 11) & 0xFF) >= T2v);
        if (take) {
          uint32_t pos = atomicAdd(&fcnt, 1u);
          if (pos < CAP) crow[pos] = ((uint64_t)bits << 32) | (uint32_t)~(uint32_t)(i * 4 + c);
        }
      }
    }
  }
  __syncthreads();

  const uint32_t M2 = fcnt < CAP ? fcnt : CAP;
  for (int i = tid; i < (int)M2; i += NTHR) {
    uint64_t key = crow[i];
    int rank = 0;
    for (uint32_t j = 0; j < M2; ++j) rank += (crow[j] > key) ? 1 : 0;
    if (rank < TOPK) {
      uint32_t bits = (uint32_t)(key >> 32);
      uint32_t idx = ~(uint32_t)(key & 0xFFFFFFFFull);
      int q = (int)(idx / NCLS);
      int cls = (int)idx - q * NCLS;
      float4 pb = brow[q];
      float x0 = fmaxf((pb.x - 0.5f * pb.z) * img_w, 0.f);
      float y0 = fmaxf((pb.y - 0.5f * pb.w) * img_h, 0.f);
      float w2 = fmaxf(pb.z * img_w, 1.f);
      float h2 = fmaxf(pb.w * img_h, 1.f);
      int o = b * TOPK + rank;
      out_labels[o] = (float)cls;
      out_boxes[o] = make_float4(x0, y0, w2, h2);
      out_scores[o] = __uint_as_float(bits);
    }
  }
}

extern "C" void kernel_launch(void* const* d_in, const int* in_sizes, int n_in,
                              void* d_out, int out_size, void* d_ws, size_t ws_size,
                              hipStream_t stream) {
  const float* logits = (const float*)d_in[0];
  const float* boxes  = (const float*)d_in[1];
  const int*   sizes  = (const int*)d_in[2];
  float*       outp   = (float*)d_out;
  (void)in_sizes; (void)n_in; (void)out_size; (void)ws_size;

  char* ws = (char*)d_ws;
  uint64_t* cand_g = (uint64_t*)(ws + WS_CAND);
  uint32_t* cnt_g  = (uint32_t*)(ws + WS_CNT);
  uint32_t* done_g = (uint32_t*)(ws + WS_DONE);

  rtdetr_fused<<<BATCH * SPLIT, NTHR, 0, stream>>>(logits, boxes, sizes, outp,
                                                   cand_g, cnt_g, done_g);
}

// Round 9
// 26.870 us; speedup vs baseline: 14.6155x; 14.6155x over previous
//
#include <hip/hip_runtime.h>
#include <stdint.h>

// RT-DETR post-processing, round 9 = R8 with the compile fix: nontemporal
// load needs a native clang ext_vector type, not HIP_vector_type<float,4>.
// k1: perfectly-coalesced stride-NTHR 16B/lane loads + nontemporal hint.
// R7 lesson: NO cross-block agent-scope fences. Two plain dispatches.
// Selection semantics (proven R1-R6, absmax 0): top-300 by composite key
// (sigmoid_bits<<32)|~idx == (score desc, index asc) exactly.

#define BATCH 128
#define NCLS 80
#define NQ 2000
#define ROW (NQ * NCLS)     // 160000
#define TOPK 300
#define SPLIT 16
#define CHUNK (ROW / SPLIT) // 10000 floats = 2500 float4
#define SEGCAP 128
#define CAP (SPLIT * SEGCAP) // 2048
#define KEEPCAP 512
#define LOGIT_T 2.6f
#define NTHR 256

typedef float floatx4 __attribute__((ext_vector_type(4)));

// ws layout (bytes), nothing pre-zeroed:
//   cand : [BATCH][SPLIT][SEGCAP] u64 @ 0       (2 MB)
//   cnt  : [BATCH][SPLIT] u32        @ WS_CNT   (8 KB)
#define WS_CAND 0
#define WS_CNT  (BATCH * SPLIT * SEGCAP * 8)

__device__ __forceinline__ uint32_t score_bits(float x) {
  float e = expf(-fabsf(x));
  float num = (x >= 0.f) ? 1.f : e;
  float s = num / (1.f + e);
  return __float_as_uint(s);
}

__device__ __forceinline__ uint32_t bin512(uint32_t bits) {
  // monotone over the candidate range (sigmoid(2.6)=0.9309.. -> bits
  // 0x3F6E4xxx..0x3F7FFFFF, where >>12 has constant high bits)
  return (bits >= 0x3F800000u) ? 511u : ((bits >> 12) & 0x1FFu);
}

// ---- k1: coalesced nontemporal stream, gate raw logit > 2.6 ----
__global__ __launch_bounds__(NTHR)
void k1_collect(const float* __restrict__ logits,
                uint64_t* __restrict__ cand_g,
                uint32_t* __restrict__ cnt_g)
{
  __shared__ uint32_t lcnt;
  const int row = blockIdx.x >> 4;          // SPLIT=16
  const int part = blockIdx.x & 15;
  const int tid = threadIdx.x;
  if (tid == 0) lcnt = 0;
  __syncthreads();

  const floatx4* p = (const floatx4*)(logits + (size_t)row * ROW + part * CHUNK);
  uint64_t* seg = cand_g + ((size_t)row * SPLIT + part) * SEGCAP;
  const uint32_t base_idx = part * CHUNK;

  for (int i = tid; i < CHUNK / 4; i += NTHR) {
    floatx4 v = __builtin_nontemporal_load(p + i);
    float m = fmaxf(fmaxf(v.x, v.y), fmaxf(v.z, v.w));
    if (m > LOGIT_T) {
      #pragma unroll
      for (int c = 0; c < 4; ++c) {
        float x = v[c];
        if (x > LOGIT_T) {
          uint32_t pos = atomicAdd(&lcnt, 1u);
          uint32_t idx = base_idx + i * 4 + c;
          if (pos < SEGCAP) seg[pos] = ((uint64_t)score_bits(x) << 32) | (uint32_t)~idx;
        }
      }
    }
  }
  __syncthreads();
  if (tid == 0) cnt_g[row * SPLIT + part] = lcnt;  // plain store
}

// ---- k2: prefix, compact, hist-cut exact rank, emit; inline fallback ----
#define NB 8192

__global__ __launch_bounds__(1024, 1)
void k2_rank(const uint64_t* __restrict__ cand_g,
             const uint32_t* __restrict__ cnt_g,
             const float* __restrict__ logits,
             const float* __restrict__ boxes,
             const int* __restrict__ sizes,
             float* __restrict__ out)
{
  __shared__ uint64_t cand[CAP];        // 16 KB (shared with fallback)
  __shared__ uint64_t keep[KEEPCAP];    // 4 KB
  __shared__ uint32_t hist[512];        // 2 KB
  __shared__ uint32_t pc[SPLIT], pfx[SPLIT];
  __shared__ uint32_t sh_bad, sh_M, keepcnt, sh_B;
  // fallback-only:
  __shared__ uint32_t fhist[NB];        // 32 KB
  __shared__ uint32_t fcsum[1024];      // 4 KB
  __shared__ uint32_t fhist2[256];      // 1 KB
  __shared__ uint32_t sh_T, sh_A2, sh_T2, sh_cnt;

  const int b = blockIdx.x;
  const int tid = threadIdx.x;

  float* out_labels = out;
  float4* out_boxes = (float4*)(out + BATCH * TOPK);
  float* out_scores = out + BATCH * TOPK + BATCH * TOPK * 4;
  const float4* brow = (const float4*)(boxes + (size_t)b * NQ * 4);
  const float img_h = (float)sizes[2 * b];
  const float img_w = (float)sizes[2 * b + 1];

  if (tid < 512) hist[tid] = 0;
  if (tid == 0) keepcnt = 0;

  // parallel count load + wave-0 shuffle scan
  if (tid < 64) {
    uint32_t c = (tid < SPLIT) ? cnt_g[b * SPLIT + tid] : 0;
    uint32_t incl = c;
    #pragma unroll
    for (int d = 1; d < 16; d <<= 1) {
      uint32_t o = __shfl_up(incl, d, 64);
      if (tid >= d) incl += o;
    }
    if (tid < SPLIT) { pc[tid] = c; pfx[tid] = incl - c; }
    uint32_t total = __shfl(incl, SPLIT - 1, 64);
    unsigned long long over = __ballot(tid < SPLIT && c > SEGCAP);
    if (tid == 0) {
      sh_M = total;
      sh_bad = (over != 0ull || total < TOPK) ? 1u : 0u;
    }
  }
  __syncthreads();

  if (!sh_bad) {
    const uint32_t M = sh_M;
    const uint64_t* crow = cand_g + (size_t)b * SPLIT * SEGCAP;

    // parallel compaction: thread t -> part t>>6, slot r*64+(t&63)
    {
      const int p = tid >> 6;
      const int jl = tid & 63;
      #pragma unroll
      for (int r = 0; r < SEGCAP / 64; ++r) {
        int j = r * 64 + jl;
        if (j < (int)pc[p]) cand[pfx[p] + j] = crow[p * SEGCAP + j];
      }
    }
    __syncthreads();

    // 512-bin histogram of candidate score bits
    for (int i = tid; i < (int)M; i += 1024)
      atomicAdd(&hist[bin512((uint32_t)(cand[i] >> 32))], 1u);
    __syncthreads();

    // threshold super-bin (coarse, 8-bin granularity): keep = bins >= B
    if (tid < 64) {
      const int lane = tid;
      uint32_t s = 0;
      #pragma unroll
      for (int j = 0; j < 8; ++j) s += hist[lane * 8 + j];
      uint32_t suf = s;
      #pragma unroll
      for (int d = 1; d < 64; d <<= 1) {
        uint32_t o = __shfl_down(suf, d, 64);
        if (lane + d < 64) suf += o;
      }
      unsigned long long m = __ballot(suf >= (uint32_t)TOPK);
      int L = 63 - __builtin_clzll(m);    // exists since M >= TOPK
      if (lane == 0) sh_B = (uint32_t)(L * 8);
    }
    __syncthreads();

    // compact keep set (superset of top-300)
    const uint32_t Bbin = sh_B;
    for (int i = tid; i < (int)M; i += 1024) {
      uint64_t key = cand[i];
      if (bin512((uint32_t)(key >> 32)) >= Bbin) {
        uint32_t pos = atomicAdd(&keepcnt, 1u);
        if (pos < KEEPCAP) keep[pos] = key;
      }
    }
    __syncthreads();
    const uint32_t KN = keepcnt;

    if (KN <= KEEPCAP) {
      for (int i = tid; i < (int)KN; i += 1024) {
        uint64_t key = keep[i];
        int rank = 0;
        for (uint32_t j = 0; j < KN; ++j) rank += (keep[j] > key) ? 1 : 0;
        if (rank < TOPK) {
          uint32_t bits = (uint32_t)(key >> 32);
          uint32_t idx = ~(uint32_t)(key & 0xFFFFFFFFull);
          int q = (int)(idx / NCLS);
          int cls = (int)idx - q * NCLS;
          float4 pb = brow[q];
          float x0 = fmaxf((pb.x - 0.5f * pb.z) * img_w, 0.f);
          float y0 = fmaxf((pb.y - 0.5f * pb.w) * img_h, 0.f);
          float w2 = fmaxf(pb.z * img_w, 1.f);
          float h2 = fmaxf(pb.w * img_h, 1.f);
          int o = b * TOPK + rank;
          out_labels[o] = (float)cls;
          out_boxes[o] = make_float4(x0, y0, w2, h2);
          out_scores[o] = __uint_as_float(bits);
        }
      }
    } else {
      // keep overflow (pathological distribution): exact O(M^2) on cand
      for (int i = tid; i < (int)M; i += 1024) {
        uint64_t key = cand[i];
        int rank = 0;
        for (uint32_t j = 0; j < M; ++j) rank += (cand[j] > key) ? 1 : 0;
        if (rank < TOPK) {
          uint32_t bits = (uint32_t)(key >> 32);
          uint32_t idx = ~(uint32_t)(key & 0xFFFFFFFFull);
          int q = (int)(idx / NCLS);
          int cls = (int)idx - q * NCLS;
          float4 pb = brow[q];
          float x0 = fmaxf((pb.x - 0.5f * pb.z) * img_w, 0.f);
          float y0 = fmaxf((pb.y - 0.5f * pb.w) * img_h, 0.f);
          float w2 = fmaxf(pb.z * img_w, 1.f);
          float h2 = fmaxf(pb.w * img_h, 1.f);
          int o = b * TOPK + rank;
          out_labels[o] = (float)cls;
          out_boxes[o] = make_float4(x0, y0, w2, h2);
          out_scores[o] = __uint_as_float(bits);
        }
      }
    }
    return;
  }

  // ======== inline exact full-row fallback (R1's proven algorithm) ========
  const float4* row4 = (const float4*)(logits + (size_t)b * ROW);

  for (int i = tid; i < NB; i += 1024) fhist[i] = 0;
  if (tid == 0) sh_cnt = 0;
  __syncthreads();

  for (int i = tid; i < ROW / 4; i += 1024) {
    float4 v = row4[i];
    #pragma unroll
    for (int c = 0; c < 4; ++c) {
      uint32_t bk = score_bits((&v.x)[c]) >> 17;
      bk = bk < NB ? bk : NB - 1;
      atomicAdd(&fhist[bk], 1u);
    }
  }
  __syncthreads();

  {
    uint32_t s = 0;
    #pragma unroll
    for (int j = 0; j < NB / 1024; ++j) s += fhist[tid * (NB / 1024) + j];
    fcsum[tid] = s;
  }
  __syncthreads();

  if (tid < 64) {
    const int lane = tid;
    uint32_t ss = 0;
    if (lane < 32) {
      #pragma unroll
      for (int j = 0; j < 32; ++j) ss += fcsum[lane * 32 + j];
    }
    uint32_t suf = ss;
    #pragma unroll
    for (int d = 1; d < 32; d <<= 1) {
      uint32_t o = __shfl_down(suf, d, 64);
      if (lane + d < 32) suf += o;
    }
    unsigned long long m = __ballot(lane < 32 && suf >= (uint32_t)TOPK);
    int sc = 63 - __builtin_clzll(m);
    uint32_t acc0 = __shfl(suf, sc + 1, 64);

    uint32_t cs = (lane < 32) ? fcsum[sc * 32 + lane] : 0;
    uint32_t suf2 = cs;
    #pragma unroll
    for (int d = 1; d < 32; d <<= 1) {
      uint32_t o = __shfl_down(suf2, d, 64);
      if (lane + d < 32) suf2 += o;
    }
    m = __ballot(lane < 32 && (acc0 + suf2) >= (uint32_t)TOPK);
    int ch = 63 - __builtin_clzll(m);
    uint32_t acc1 = acc0 + __shfl(suf2, ch + 1, 64);
    int chunk = sc * 32 + ch;

    uint32_t hv = (lane < 8) ? fhist[chunk * 8 + lane] : 0;
    uint32_t suf3 = hv;
    #pragma unroll
    for (int d = 1; d < 8; d <<= 1) {
      uint32_t o = __shfl_down(suf3, d, 64);
      if (lane + d < 8) suf3 += o;
    }
    m = __ballot(lane < 8 && (acc1 + suf3) >= (uint32_t)TOPK);
    int bk = 63 - __builtin_clzll(m);
    uint32_t A = acc1 + __shfl(suf3, bk + 1, 64);
    if (lane == 0) { sh_T = (uint32_t)(chunk * 8 + bk); sh_A2 = A; }
  }
  __syncthreads();

  const uint32_t T = sh_T;
  const uint32_t A = sh_A2;
  const uint32_t C = fhist[T];

  if (A + C <= CAP) {
    for (int i = tid; i < ROW / 4; i += 1024) {
      float4 v = row4[i];
      #pragma unroll
      for (int c = 0; c < 4; ++c) {
        uint32_t bits = score_bits((&v.x)[c]);
        uint32_t bk2 = bits >> 17; bk2 = bk2 < NB ? bk2 : NB - 1;
        if (bk2 >= T) {
          uint32_t pos = atomicAdd(&sh_cnt, 1u);
          cand[pos] = ((uint64_t)bits << 32) | (uint32_t)~(uint32_t)(i * 4 + c);
        }
      }
    }
  } else {
    for (int i = tid; i < 256; i += 1024) fhist2[i] = 0;
    __syncthreads();
    for (int i = tid; i < ROW / 4; i += 1024) {
      float4 v = row4[i];
      #pragma unroll
      for (int c = 0; c < 4; ++c) {
        uint32_t bits = score_bits((&v.x)[c]);
        uint32_t bk2 = bits >> 17; bk2 = bk2 < NB ? bk2 : NB - 1;
        if (bk2 == T) atomicAdd(&fhist2[(bits >> 9) & 0xFF], 1u);
      }
    }
    __syncthreads();
    if (tid < 64) {
      const int lane = tid;
      uint32_t h4 = 0;
      #pragma unroll
      for (int j = 0; j < 4; ++j) h4 += fhist2[lane * 4 + j];
      uint32_t suf = h4;
      #pragma unroll
      for (int d = 1; d < 64; d <<= 1) {
        uint32_t o = __shfl_down(suf, d, 64);
        if (lane + d < 64) suf += o;
      }
      unsigned long long m = __ballot((A + suf) >= (uint32_t)TOPK);
      int g = 63 - __builtin_clzll(m);
      uint32_t accg = A + ((g < 63) ? __shfl(suf, g + 1, 64) : 0u);
      uint32_t hb = (lane < 4) ? fhist2[g * 4 + lane] : 0;
      uint32_t sufb = hb;
      #pragma unroll
      for (int d = 1; d < 4; d <<= 1) {
        uint32_t o = __shfl_down(sufb, d, 64);
        if (lane + d < 4) sufb += o;
      }
      m = __ballot(lane < 4 && (accg + sufb) >= (uint32_t)TOPK);
      int bin = 63 - __builtin_clzll(m);
      if (lane == 0) sh_T2 = (uint32_t)(g * 4 + bin);
    }
    __syncthreads();
    const uint32_t T2 = sh_T2;
    for (int i = tid; i < ROW / 4; i += 1024) {
      float4 v = row4[i];
      #pragma unroll
      for (int c = 0; c < 4; ++c) {
        uint32_t bits = score_bits((&v.x)[c]);
        uint32_t bk2 = bits >> 17; bk2 = bk2 < NB ? bk2 : NB - 1;
        bool take = (bk2 > T) || (bk2 == T && ((bits >> 9) & 0xFF) >= T2);
        if (take) {
          uint32_t pos = atomicAdd(&sh_cnt, 1u);
          if (pos < CAP) cand[pos] = ((uint64_t)bits << 32) | (uint32_t)~(uint32_t)(i * 4 + c);
        }
      }
    }
  }
  __syncthreads();

  const uint32_t M = sh_cnt < CAP ? sh_cnt : CAP;
  for (int i = tid; i < (int)M; i += 1024) {
    uint64_t key = cand[i];
    int rank = 0;
    for (uint32_t mi = 0; mi < M; ++mi) rank += (cand[mi] > key) ? 1 : 0;
    if (rank < TOPK) {
      uint32_t bits = (uint32_t)(key >> 32);
      uint32_t idx = ~(uint32_t)(key & 0xFFFFFFFFull);
      int q = (int)(idx / NCLS);
      int cls = (int)idx - q * NCLS;
      float4 pb = brow[q];
      float x0 = fmaxf((pb.x - 0.5f * pb.z) * img_w, 0.f);
      float y0 = fmaxf((pb.y - 0.5f * pb.w) * img_h, 0.f);
      float w2 = fmaxf(pb.z * img_w, 1.f);
      float h2 = fmaxf(pb.w * img_h, 1.f);
      int o = b * TOPK + rank;
      out_labels[o] = (float)cls;
      out_boxes[o] = make_float4(x0, y0, w2, h2);
      out_scores[o] = __uint_as_float(bits);
    }
  }
}

extern "C" void kernel_launch(void* const* d_in, const int* in_sizes, int n_in,
                              void* d_out, int out_size, void* d_ws, size_t ws_size,
                              hipStream_t stream) {
  const float* logits = (const float*)d_in[0];
  const float* boxes  = (const float*)d_in[1];
  const int*   sizes  = (const int*)d_in[2];
  float*       outp   = (float*)d_out;
  (void)in_sizes; (void)n_in; (void)out_size; (void)ws_size;

  char* ws = (char*)d_ws;
  uint64_t* cand_g = (uint64_t*)(ws + WS_CAND);
  uint32_t* cnt_g  = (uint32_t*)(ws + WS_CNT);

  k1_collect<<<BATCH * SPLIT, NTHR, 0, stream>>>(logits, cand_g, cnt_g);
  k2_rank<<<BATCH, 1024, 0, stream>>>(cand_g, cnt_g, logits, boxes, sizes, outp);
}